// Round 5
// baseline (134.893 us; speedup 1.0000x reference)
//
#include <hip/hip_runtime.h>

#define EPS 1e-6f

typedef unsigned short u16;
typedef u16   u16x4  __attribute__((ext_vector_type(4)));
typedef u16   u16x8  __attribute__((ext_vector_type(8)));
typedef float f32x4  __attribute__((ext_vector_type(4)));
typedef short s16x8  __attribute__((ext_vector_type(8)));   // 8 bf16 as raw i16 (4 VGPRs)

enum { BR_LIN = 0, BR_R6, BR_R5, BR_MIN, BR_R3, BR_XY, BR_R1, BR_R0 };

// ---------------- helpers ----------------
__device__ __forceinline__ u16 f2bf(float f) { return __builtin_bit_cast(u16, (__bf16)f); }
__device__ __forceinline__ float bf2f(u16 b) { return (float)__builtin_bit_cast(__bf16, b); }

__device__ __forceinline__ s16x8 lds_bf8(const u16* p) {
  u16x8 r = *(const u16x8*)p;
  return __builtin_bit_cast(s16x8, r);
}

__device__ __forceinline__ f32x4 mfma16(s16x8 a, s16x8 b, f32x4 c) {
  return __builtin_amdgcn_mfma_f32_16x16x32_bf16(a, b, c, 0, 0, 0);
}

__device__ __forceinline__ float r_poly_f(float a) {
  float d  = 0.5f - a;
  float d2 = d * d;
  float num = 0.25f + 1.65811f * d + 2.15388f * d2 + 8.2844f * d2 * d + 6.16764f * d2 * d2;
  float den = a * (1.0f - a);
  if (fabsf(den) < EPS) den = EPS;
  return num / den;
}

__device__ __forceinline__ float pmean(float X, float Y, float r, float rinv, float w0, float w1) {
  float tx = exp2f(r * log2f(X));
  float ty = exp2f(r * log2f(Y));
  float s  = w0 * tx + w1 * ty;
  return exp2f(rinv * log2f(s));
}

__device__ __forceinline__ float combine_step(float carry, float leaf, const float* p) {
  float w0 = p[0], w1 = p[1], a_fb = p[2];
  float c0 = p[3], c1 = p[4], c2 = p[5], c3 = p[6];
  int meta = __float_as_int(p[7]);
  int br = meta & 0xff, flip = meta >> 8;

  float xx = carry, yy = leaf;
  xx = __builtin_isnan(xx) ? EPS : xx;
  yy = __builtin_isnan(yy) ? EPS : yy;
  xx = fminf(fmaxf(xx, EPS), 1.0f - EPS);
  yy = fminf(fmaxf(yy, EPS), 1.0f - EPS);
  float X = flip ? (1.0f - xx) : xx;
  float Y = flip ? (1.0f - yy) : yy;

  float r;
  switch (br) {
    default:
    case BR_LIN: r = w0 * X + w1 * Y; break;
    case BR_R6:  r = c0 * (w0 * X + w1 * Y) + c1 * pmean(X, Y, c2, c3, w0, w1); break;
    case BR_R5:  r = pmean(X, Y, c0, c1, w0, w1); break;
    case BR_MIN: r = fminf(X, Y); break;
    case BR_R3:  r = 4.0f * (c0 * fminf(X, Y) + c1 * (X * Y)); break;
    case BR_XY:  r = X * Y; break;
    case BR_R1:  r = exp2f(c0 * log2f(X * Y)); break;
    case BR_R0:  r = (fabsf(X - 1.0f) < EPS && fabsf(Y - 1.0f) < EPS) ? 1.0f : 0.0f; break;
  }
  if (flip) r = 1.0f - r;
  if (__builtin_isnan(r)) r = a_fb;
  return r;
}

// ---------------- kernel 1: per-node chain params ----------------
__global__ void param_kernel(const float* __restrict__ W, const float* __restrict__ Bv,
                             float* __restrict__ prm, int n) {
  int i = blockIdx.x * blockDim.x + threadIdx.x;
  if (i >= n) return;
  float w0r = W[2 * i], w1r = W[2 * i + 1];
  float m  = fmaxf(w0r, w1r);
  float e0 = expf(w0r - m), e1 = expf(w1r - m);
  float inv = 1.0f / (e0 + e1);
  float w0 = e0 * inv, w1 = e1 * inv;

  float b   = Bv[i];
  float sig = 1.0f / (1.0f + expf(-b));
  float a_fb = sig * 3.0f - 1.0f;

  float a = a_fb;
  if (__builtin_isnan(a)) a = -1.0f;
  a = fminf(fmaxf(a, -1.0f + EPS), 2.0f - EPS);
  int flip = (a < 0.5f - EPS) ? 1 : 0;
  float aa = a;
  if (flip) aa = fminf(fmaxf(1.0f - a, -1.0f + EPS), 2.0f - EPS);

  int br; float c0 = 0.f, c1 = 0.f, c2 = 0.f, c3 = 0.f;
  if (fabsf(aa - 2.0f) < EPS) br = BR_R0;
  else if (aa > 1.25f && aa < 2.0f) {
    br = BR_R1;
    c0 = sqrtf(fmaxf(3.0f / fmaxf(2.0f - aa, EPS) - 1.0f, EPS));
  } else if (fabsf(aa - 1.25f) < EPS) br = BR_XY;
  else if (aa > 1.0f && aa < 1.25f) { br = BR_R3; c0 = 1.25f - aa; c1 = aa - 1.0f; }
  else if (fabsf(aa - 1.0f) < EPS) br = BR_MIN;
  else if (aa >= 0.75f && aa < 1.0f) {
    br = BR_R5;
    float ac = fminf(fmaxf(aa, 0.75f), 1.0f - EPS);
    float ra = r_poly_f(ac);
    if (fabsf(ra) < EPS) ra = EPS;
    c0 = ra; c1 = 1.0f / ra;
  } else if (aa > 0.5f && aa < 0.75f) {
    br = BR_R6;
    c0 = 3.0f - 4.0f * aa; c1 = 4.0f * aa - 2.0f;
    float R = r_poly_f(0.75f);
    if (fabsf(R) < EPS) R = EPS;
    c2 = R; c3 = 1.0f / R;
  } else br = BR_LIN;

  float* o = prm + i * 8;
  o[0] = w0; o[1] = w1; o[2] = a_fb; o[3] = c0; o[4] = c1; o[5] = c2; o[6] = c3;
  o[7] = __int_as_float(br | (flip << 8));
}

// ---------------- kernel 2: register-resident Sinkhorn ----------------
__global__ __launch_bounds__(1024, 4) void sinkhorn_kernel(
    const float* __restrict__ logits,
    u16* __restrict__ PTh, u16* __restrict__ PTl) {
  __shared__ float alpha[256], beta[256];
  __shared__ float psum[256][33];

  const int t  = threadIdx.x;
  const int R  = t >> 5;
  const int C  = t & 31;
  const int r0 = R << 3;

  float e[8][8];
  #pragma unroll
  for (int dr = 0; dr < 8; ++dr) {
    const float* row = logits + (r0 + dr) * 256 + C;
    #pragma unroll
    for (int m = 0; m < 8; ++m) e[dr][m] = __expf(row[m << 5]);
  }

  if (t < 256) beta[t] = 1.0f;
  __syncthreads();

  for (int it = 0; it < 10; ++it) {
    {
      float bv[8], acc[8];
      #pragma unroll
      for (int m = 0; m < 8; ++m) bv[m] = beta[C + (m << 5)];
      #pragma unroll
      for (int dr = 0; dr < 8; ++dr) {
        float s = 0.f;
        #pragma unroll
        for (int m = 0; m < 8; ++m) s += e[dr][m] * bv[m];
        acc[dr] = s;
      }
      #pragma unroll
      for (int dr = 0; dr < 8; ++dr) psum[r0 + dr][C] = acc[dr];
    }
    __syncthreads();
    if (t < 256) {
      float s = 0.f;
      #pragma unroll
      for (int j = 0; j < 32; ++j) s += psum[t][j];
      alpha[t] = 1.0f / s;
    }
    __syncthreads();
    {
      float av[8], acc[8];
      #pragma unroll
      for (int dr = 0; dr < 8; ++dr) av[dr] = alpha[r0 + dr];
      #pragma unroll
      for (int m = 0; m < 8; ++m) {
        float s = 0.f;
        #pragma unroll
        for (int dr = 0; dr < 8; ++dr) s += e[dr][m] * av[dr];
        acc[m] = s;
      }
      #pragma unroll
      for (int m = 0; m < 8; ++m) psum[C + (m << 5)][R] = acc[m];
    }
    __syncthreads();
    if (t < 256) {
      float s = 0.f;
      #pragma unroll
      for (int j = 0; j < 32; ++j) s += psum[t][j];
      beta[t] = 1.0f / s;
    }
    __syncthreads();
  }

  float av[8], bv[8];
  #pragma unroll
  for (int dr = 0; dr < 8; ++dr) av[dr] = alpha[r0 + dr];
  #pragma unroll
  for (int m = 0; m < 8; ++m) bv[m] = beta[C + (m << 5)];

  #pragma unroll
  for (int m = 0; m < 8; ++m) {
    int l = C + (m << 5);
    u16x8 vh, vl;
    #pragma unroll
    for (int dr = 0; dr < 8; ++dr) {
      float pv = av[dr] * e[dr][m] * bv[m];
      u16 h = f2bf(pv);
      vh[dr] = h;
      vl[dr] = f2bf(pv - bf2f(h));
    }
    *(u16x8*)(PTh + l * 256 + r0) = vh;
    *(u16x8*)(PTl + l * 256 + r0) = vl;
  }
}

// ---------------- kernel 3: fused split-bf16 MFMA GEMM + chain ----------------
// 512 threads = 8 waves in 4M x 2N grid. b-tile = 128, full L = 256, K-step 32.
// Wave (wm = w>>1, wn = w&1): rows l = wm*64 + mf*16 (mf 0..3);
// cols b = wn*64 + nf*16 (nf 0..3). acc[4][4] f32x4 = 64 VGPR.
// Staging rows padded to BSTR=40 u16 (80 B): frag-read bank starts 20r mod 32
// -> 8 distinct 4-bank spans -> 2-way (free).
// LDS 61440 B: xs_h[128][40] @0, xs_l @10240, pt_h[256][40] @20480, pt_l @40960.
// Epilogue aliases: cbuf[64][CSTR] @0 (33792 B), cprm @34048 (8160 B).
#define BSTR 40
#define CSTR 132

__global__ __launch_bounds__(512, 4) void gemm_chain_kernel(
    const float* __restrict__ x, const u16* __restrict__ PTh, const u16* __restrict__ PTl,
    const float* __restrict__ prm, float* __restrict__ out) {
  __shared__ __align__(16) char smem[61440];
  u16* xs_h = (u16*)smem;                       // [128][BSTR]
  u16* xs_l = (u16*)(smem + 10240);
  u16* pt_h = (u16*)(smem + 20480);             // [256][BSTR]
  u16* pt_l = (u16*)(smem + 40960);
  float* cbuf = (float*)smem;                   // [64][CSTR]
  float* cprm = (float*)(smem + 34048);         // 2040 floats

  const int t    = threadIdx.x;
  const int w    = t >> 6;
  const int lane = t & 63;
  const int bl   = lane & 15;
  const int kh   = lane >> 4;
  const int wm   = w >> 1;                      // 0..3 (l block)
  const int wn   = w & 1;                       // 0..1 (b block)
  const int b0   = blockIdx.x * 128;

  // staging thread mapping
  const int xrow = t >> 3;                      // 0..63 (rows xrow, xrow+64)
  const int xc4  = t & 7;                       // u16x4 slot within 32-k slice
  const int prow = t >> 2;                      // 0..127 (rows prow, prow+128)
  const int pk   = t & 3;                       // u16x8 slot within 32-k slice

  f32x4 acc[4][4];
  #pragma unroll
  for (int m = 0; m < 4; ++m)
    #pragma unroll
    for (int n = 0; n < 4; ++n) acc[m][n] = f32x4{0.f, 0.f, 0.f, 0.f};

  // prefetch registers
  f32x4 xr[2];
  u16x8 ph[2], pl[2];

  #pragma unroll
  for (int j = 0; j < 2; ++j) {
    xr[j] = *(const f32x4*)(x + (b0 + xrow + 64 * j) * 256 + (xc4 << 2));
    ph[j] = *(const u16x8*)(PTh + (prow + 128 * j) * 256 + (pk << 3));
    pl[j] = *(const u16x8*)(PTl + (prow + 128 * j) * 256 + (pk << 3));
  }

  for (int kc = 0; kc < 8; ++kc) {
    // ---- W phase: write prefetched tile to LDS ----
    #pragma unroll
    for (int j = 0; j < 2; ++j) {
      u16x4 vh, vl;
      #pragma unroll
      for (int e = 0; e < 4; ++e) {
        float f = xr[j][e];
        u16 h = f2bf(f);
        vh[e] = h;
        vl[e] = f2bf(f - bf2f(h));
      }
      *(u16x4*)(xs_h + (xrow + 64 * j) * BSTR + (xc4 << 2)) = vh;
      *(u16x4*)(xs_l + (xrow + 64 * j) * BSTR + (xc4 << 2)) = vl;
      *(u16x8*)(pt_h + (prow + 128 * j) * BSTR + (pk << 3)) = ph[j];
      *(u16x8*)(pt_l + (prow + 128 * j) * BSTR + (pk << 3)) = pl[j];
    }
    __syncthreads();

    // ---- issue prefetch for next tile (lands under C phase) ----
    if (kc < 7) {
      int k1 = (kc + 1) << 5;
      #pragma unroll
      for (int j = 0; j < 2; ++j) {
        xr[j] = *(const f32x4*)(x + (b0 + xrow + 64 * j) * 256 + k1 + (xc4 << 2));
        ph[j] = *(const u16x8*)(PTh + (prow + 128 * j) * 256 + k1 + (pk << 3));
        pl[j] = *(const u16x8*)(PTl + (prow + 128 * j) * 256 + k1 + (pk << 3));
      }
    }

    // ---- C phase: fragments + MFMA ----
    s16x8 bh[4], blo[4];
    #pragma unroll
    for (int nf = 0; nf < 4; ++nf) {
      int brow = (wn << 6) + (nf << 4) + bl;
      bh[nf]  = lds_bf8(xs_h + brow * BSTR + (kh << 3));
      blo[nf] = lds_bf8(xs_l + brow * BSTR + (kh << 3));
    }
    #pragma unroll
    for (int mf = 0; mf < 4; ++mf) {
      int arow = (wm << 6) + (mf << 4) + bl;
      s16x8 ah = lds_bf8(pt_h + arow * BSTR + (kh << 3));
      s16x8 al = lds_bf8(pt_l + arow * BSTR + (kh << 3));
      #pragma unroll
      for (int nf = 0; nf < 4; ++nf) {
        acc[mf][nf] = mfma16(ah, bh[nf],  acc[mf][nf]);
        acc[mf][nf] = mfma16(ah, blo[nf], acc[mf][nf]);
        acc[mf][nf] = mfma16(al, bh[nf],  acc[mf][nf]);
      }
    }
    __syncthreads();
  }

  // ---- chain params into LDS (aliases dead pt staging) ----
  for (int j = t; j < 2040; j += 512) cprm[j] = prm[j];

  float carry = 0.0f;

  #pragma unroll
  for (int c = 0; c < 4; ++c) {
    __syncthreads();
    // waves with wm == c dump l-chunk [64c, 64c+64) into cbuf[l'][b]
    if (wm == c) {
      #pragma unroll
      for (int mf = 0; mf < 4; ++mf) {
        #pragma unroll
        for (int nf = 0; nf < 4; ++nf) {
          int bc = (wn << 6) + (nf << 4) + bl;
          #pragma unroll
          for (int r = 0; r < 4; ++r) {
            int lr = (mf << 4) + (kh << 2) + r;
            cbuf[lr * CSTR + bc] = acc[mf][nf][r];
          }
        }
      }
    }
    __syncthreads();
    if (t < 128) {
      for (int lc = 0; lc < 64; lc += 4) {
        float v[4];
        #pragma unroll
        for (int u = 0; u < 4; ++u) v[u] = cbuf[(lc + u) * CSTR + t];
        #pragma unroll
        for (int u = 0; u < 4; ++u) {
          int l = (c << 6) + lc + u;
          carry = (l == 0) ? v[u] : combine_step(carry, v[u], cprm + ((l - 1) << 3));
        }
      }
    }
  }
  if (t < 128) out[b0 + t] = carry;
}

// ---------------- launch ----------------
extern "C" void kernel_launch(void* const* d_in, const int* in_sizes, int n_in,
                              void* d_out, int out_size, void* d_ws, size_t ws_size,
                              hipStream_t stream) {
  const float* x       = (const float*)d_in[0];   // (65536, 256)
  const float* logits  = (const float*)d_in[1];   // (256, 256)
  const float* weights = (const float*)d_in[2];   // (255, 2)
  const float* biases  = (const float*)d_in[3];   // (255,)
  float* out = (float*)d_out;                     // (65536, 1)

  char* ws = (char*)d_ws;
  u16*   PTh = (u16*)ws;                          // 131072 B
  u16*   PTl = (u16*)(ws + 131072);               // 131072 B
  float* prm = (float*)(ws + 262144);             // 8160 B

  int Btot = in_sizes[0] / 256;                   // 65536

  param_kernel<<<1, 256, 0, stream>>>(weights, biases, prm, 255);
  sinkhorn_kernel<<<1, 1024, 0, stream>>>(logits, PTh, PTl);
  gemm_chain_kernel<<<Btot / 128, 512, 0, stream>>>(x, PTh, PTl, prm, out);
}

// Round 6
// 117.808 us; speedup vs baseline: 1.1450x; 1.1450x over previous
//
#include <hip/hip_runtime.h>

#define EPS 1e-6f

typedef unsigned short u16;
typedef u16   u16x4  __attribute__((ext_vector_type(4)));
typedef u16   u16x8  __attribute__((ext_vector_type(8)));
typedef float f32x4  __attribute__((ext_vector_type(4)));
typedef _Float16 f16x8 __attribute__((ext_vector_type(8)));

enum { BR_LIN = 0, BR_R6, BR_R5, BR_MIN, BR_R3, BR_XY, BR_R1, BR_R0 };

// ---------------- helpers ----------------
__device__ __forceinline__ u16 f2h(float f) { return __builtin_bit_cast(u16, (_Float16)f); }

__device__ __forceinline__ f16x8 lds_f16x8(const u16* p) {
  u16x8 r = *(const u16x8*)p;
  return __builtin_bit_cast(f16x8, r);
}

__device__ __forceinline__ f32x4 mfma16(f16x8 a, f16x8 b, f32x4 c) {
  return __builtin_amdgcn_mfma_f32_16x16x32_f16(a, b, c, 0, 0, 0);
}

__device__ __forceinline__ float r_poly_f(float a) {
  float d  = 0.5f - a;
  float d2 = d * d;
  float num = 0.25f + 1.65811f * d + 2.15388f * d2 + 8.2844f * d2 * d + 6.16764f * d2 * d2;
  float den = a * (1.0f - a);
  if (fabsf(den) < EPS) den = EPS;
  return num / den;
}

__device__ __forceinline__ float pmean(float X, float Y, float r, float rinv, float w0, float w1) {
  float tx = exp2f(r * log2f(X));
  float ty = exp2f(r * log2f(Y));
  float s  = w0 * tx + w1 * ty;
  return exp2f(rinv * log2f(s));
}

__device__ __forceinline__ float combine_step(float carry, float leaf, const float* p) {
  float w0 = p[0], w1 = p[1], a_fb = p[2];
  float c0 = p[3], c1 = p[4], c2 = p[5], c3 = p[6];
  int meta = __float_as_int(p[7]);
  int br = meta & 0xff, flip = meta >> 8;

  float xx = carry, yy = leaf;
  xx = __builtin_isnan(xx) ? EPS : xx;
  yy = __builtin_isnan(yy) ? EPS : yy;
  xx = fminf(fmaxf(xx, EPS), 1.0f - EPS);
  yy = fminf(fmaxf(yy, EPS), 1.0f - EPS);
  float X = flip ? (1.0f - xx) : xx;
  float Y = flip ? (1.0f - yy) : yy;

  float r;
  switch (br) {
    default:
    case BR_LIN: r = w0 * X + w1 * Y; break;
    case BR_R6:  r = c0 * (w0 * X + w1 * Y) + c1 * pmean(X, Y, c2, c3, w0, w1); break;
    case BR_R5:  r = pmean(X, Y, c0, c1, w0, w1); break;
    case BR_MIN: r = fminf(X, Y); break;
    case BR_R3:  r = 4.0f * (c0 * fminf(X, Y) + c1 * (X * Y)); break;
    case BR_XY:  r = X * Y; break;
    case BR_R1:  r = exp2f(c0 * log2f(X * Y)); break;
    case BR_R0:  r = (fabsf(X - 1.0f) < EPS && fabsf(Y - 1.0f) < EPS) ? 1.0f : 0.0f; break;
  }
  if (flip) r = 1.0f - r;
  if (__builtin_isnan(r)) r = a_fb;
  return r;
}

// ---------------- kernel 1: per-node chain params ----------------
__global__ void param_kernel(const float* __restrict__ W, const float* __restrict__ Bv,
                             float* __restrict__ prm, int n) {
  int i = blockIdx.x * blockDim.x + threadIdx.x;
  if (i >= n) return;
  float w0r = W[2 * i], w1r = W[2 * i + 1];
  float m  = fmaxf(w0r, w1r);
  float e0 = expf(w0r - m), e1 = expf(w1r - m);
  float inv = 1.0f / (e0 + e1);
  float w0 = e0 * inv, w1 = e1 * inv;

  float b   = Bv[i];
  float sig = 1.0f / (1.0f + expf(-b));
  float a_fb = sig * 3.0f - 1.0f;

  float a = a_fb;
  if (__builtin_isnan(a)) a = -1.0f;
  a = fminf(fmaxf(a, -1.0f + EPS), 2.0f - EPS);
  int flip = (a < 0.5f - EPS) ? 1 : 0;
  float aa = a;
  if (flip) aa = fminf(fmaxf(1.0f - a, -1.0f + EPS), 2.0f - EPS);

  int br; float c0 = 0.f, c1 = 0.f, c2 = 0.f, c3 = 0.f;
  if (fabsf(aa - 2.0f) < EPS) br = BR_R0;
  else if (aa > 1.25f && aa < 2.0f) {
    br = BR_R1;
    c0 = sqrtf(fmaxf(3.0f / fmaxf(2.0f - aa, EPS) - 1.0f, EPS));
  } else if (fabsf(aa - 1.25f) < EPS) br = BR_XY;
  else if (aa > 1.0f && aa < 1.25f) { br = BR_R3; c0 = 1.25f - aa; c1 = aa - 1.0f; }
  else if (fabsf(aa - 1.0f) < EPS) br = BR_MIN;
  else if (aa >= 0.75f && aa < 1.0f) {
    br = BR_R5;
    float ac = fminf(fmaxf(aa, 0.75f), 1.0f - EPS);
    float ra = r_poly_f(ac);
    if (fabsf(ra) < EPS) ra = EPS;
    c0 = ra; c1 = 1.0f / ra;
  } else if (aa > 0.5f && aa < 0.75f) {
    br = BR_R6;
    c0 = 3.0f - 4.0f * aa; c1 = 4.0f * aa - 2.0f;
    float R = r_poly_f(0.75f);
    if (fabsf(R) < EPS) R = EPS;
    c2 = R; c3 = 1.0f / R;
  } else br = BR_LIN;

  float* o = prm + i * 8;
  o[0] = w0; o[1] = w1; o[2] = a_fb; o[3] = c0; o[4] = c1; o[5] = c2; o[6] = c3;
  o[7] = __int_as_float(br | (flip << 8));
}

// ---------------- kernel 2: register-resident Sinkhorn (fp16 PT out) ----------------
__global__ __launch_bounds__(1024, 4) void sinkhorn_kernel(
    const float* __restrict__ logits, u16* __restrict__ PTf) {
  __shared__ float alpha[256], beta[256];
  __shared__ float psum[256][33];

  const int t  = threadIdx.x;
  const int R  = t >> 5;
  const int C  = t & 31;
  const int r0 = R << 3;

  float e[8][8];
  #pragma unroll
  for (int dr = 0; dr < 8; ++dr) {
    const float* row = logits + (r0 + dr) * 256 + C;
    #pragma unroll
    for (int m = 0; m < 8; ++m) e[dr][m] = __expf(row[m << 5]);
  }

  if (t < 256) beta[t] = 1.0f;
  __syncthreads();

  for (int it = 0; it < 10; ++it) {
    {
      float bv[8], acc[8];
      #pragma unroll
      for (int m = 0; m < 8; ++m) bv[m] = beta[C + (m << 5)];
      #pragma unroll
      for (int dr = 0; dr < 8; ++dr) {
        float s = 0.f;
        #pragma unroll
        for (int m = 0; m < 8; ++m) s += e[dr][m] * bv[m];
        acc[dr] = s;
      }
      #pragma unroll
      for (int dr = 0; dr < 8; ++dr) psum[r0 + dr][C] = acc[dr];
    }
    __syncthreads();
    if (t < 256) {
      float s = 0.f;
      #pragma unroll
      for (int j = 0; j < 32; ++j) s += psum[t][j];
      alpha[t] = 1.0f / s;
    }
    __syncthreads();
    {
      float av[8], acc[8];
      #pragma unroll
      for (int dr = 0; dr < 8; ++dr) av[dr] = alpha[r0 + dr];
      #pragma unroll
      for (int m = 0; m < 8; ++m) {
        float s = 0.f;
        #pragma unroll
        for (int dr = 0; dr < 8; ++dr) s += e[dr][m] * av[dr];
        acc[m] = s;
      }
      #pragma unroll
      for (int m = 0; m < 8; ++m) psum[C + (m << 5)][R] = acc[m];
    }
    __syncthreads();
    if (t < 256) {
      float s = 0.f;
      #pragma unroll
      for (int j = 0; j < 32; ++j) s += psum[t][j];
      beta[t] = 1.0f / s;
    }
    __syncthreads();
  }

  float av[8], bv[8];
  #pragma unroll
  for (int dr = 0; dr < 8; ++dr) av[dr] = alpha[r0 + dr];
  #pragma unroll
  for (int m = 0; m < 8; ++m) bv[m] = beta[C + (m << 5)];

  #pragma unroll
  for (int m = 0; m < 8; ++m) {
    int l = C + (m << 5);
    u16x8 vh;
    #pragma unroll
    for (int dr = 0; dr < 8; ++dr) vh[dr] = f2h(av[dr] * e[dr][m] * bv[m]);
    *(u16x8*)(PTf + l * 256 + r0) = vh;
  }
}

// ---------------- kernel 3: fused fp16 single-pass MFMA GEMM + chain ----------------
// 512 threads = 8 waves, 2M x 4N. b-tile 128, L=256, K-step 32, 1 MFMA pass.
// Wave (wm=w>>2, wn=w&3): rows l = wm*128 + mf*16 (mf 0..7); cols b = wn*32 + nf*16 (nf 0..1).
// LDS rows 32 u16 (64B); 16B groups XOR-swizzled: slot s = g ^ ((row>>1)&3)
// -> all b128 frag reads are 2-way bank aliased (free).  PT staged with
// pre-swizzled GLOBAL source + linear LDS writes (rule: both sides same involution).
// LDS 41984B: xs[128][32] @0 (8KB), pt[256][32] @8192 (16KB);
// epilogue alias: cbuf[64][CSTR] @0 (33792B), cprm @33792 (8160B).
#define CSTR 132

__global__ __launch_bounds__(512, 4) void gemm_chain_kernel(
    const float* __restrict__ x, const u16* __restrict__ PTf,
    const float* __restrict__ prm, float* __restrict__ out) {
  __shared__ __align__(16) char smem[41984];
  u16* xs = (u16*)smem;                      // [128][32] fp16 (swizzled groups)
  u16* pt = (u16*)(smem + 8192);             // [256][32] fp16 (swizzled groups)
  float* cbuf = (float*)smem;                // [64][CSTR]
  float* cprm = (float*)(smem + 33792);      // 2040 floats

  const int t    = threadIdx.x;
  const int w    = t >> 6;
  const int lane = t & 63;
  const int bl   = lane & 15;
  const int kh   = lane >> 4;
  const int wm   = w >> 2;                   // 0..1
  const int wn   = w & 3;                    // 0..3
  const int b0   = blockIdx.x * 128;

  const int xrow = t >> 3;                   // 0..63 (rows xrow, xrow+64)
  const int xc4  = t & 7;                    // f32x4 slot in 32-float slice

  f32x4 acc[8][2];
  #pragma unroll
  for (int m = 0; m < 8; ++m) {
    acc[m][0] = f32x4{0.f, 0.f, 0.f, 0.f};
    acc[m][1] = f32x4{0.f, 0.f, 0.f, 0.f};
  }

  f32x4 xr[2];
  u16x8 pr[2];

  // ---- prologue: prefetch tile 0 (PT with pre-swizzled source) ----
  #pragma unroll
  for (int j = 0; j < 2; ++j) {
    xr[j] = *(const f32x4*)(x + (b0 + xrow + 64 * j) * 256 + (xc4 << 2));
    int c = t + 512 * j, r = c >> 2, s = c & 3, g = s ^ ((r >> 1) & 3);
    pr[j] = *(const u16x8*)(PTf + r * 256 + (g << 3));
  }

  for (int kc = 0; kc < 8; ++kc) {
    // ---- W phase ----
    #pragma unroll
    for (int j = 0; j < 2; ++j) {
      int row = xrow + 64 * j;
      u16x4 hv;
      #pragma unroll
      for (int e = 0; e < 4; ++e) hv[e] = f2h(xr[j][e]);
      int g = xc4 >> 1, sub = xc4 & 1;
      *(u16x4*)(xs + row * 32 + ((g ^ ((row >> 1) & 3)) << 3) + (sub << 2)) = hv;
      *(u16x8*)(pt + ((t + 512 * j) << 3)) = pr[j];   // linear (content pre-swizzled)
    }
    __syncthreads();

    // ---- prefetch next tile (lands under C phase) ----
    if (kc < 7) {
      int k1 = (kc + 1) << 5;
      #pragma unroll
      for (int j = 0; j < 2; ++j) {
        xr[j] = *(const f32x4*)(x + (b0 + xrow + 64 * j) * 256 + k1 + (xc4 << 2));
        int c = t + 512 * j, r = c >> 2, s = c & 3, g = s ^ ((r >> 1) & 3);
        pr[j] = *(const u16x8*)(PTf + r * 256 + k1 + (g << 3));
      }
    }

    // ---- C phase ----
    f16x8 bh[2];
    #pragma unroll
    for (int nf = 0; nf < 2; ++nf) {
      int brow = (wn << 5) + (nf << 4) + bl;
      bh[nf] = lds_f16x8(xs + brow * 32 + ((kh ^ ((brow >> 1) & 3)) << 3));
    }
    #pragma unroll
    for (int mf = 0; mf < 8; ++mf) {
      int arow = (wm << 7) + (mf << 4) + bl;
      f16x8 ah = lds_f16x8(pt + arow * 32 + ((kh ^ ((arow >> 1) & 3)) << 3));
      #pragma unroll
      for (int nf = 0; nf < 2; ++nf)
        acc[mf][nf] = mfma16(ah, bh[nf], acc[mf][nf]);
    }
    __syncthreads();
  }

  // ---- chain params into LDS (region disjoint from staging) ----
  for (int j = t; j < 2040; j += 512) cprm[j] = prm[j];

  float carry = 0.0f;

  #pragma unroll
  for (int c = 0; c < 4; ++c) {
    __syncthreads();
    // waves with wm == c>>1 dump l-chunk [64c, 64c+64) into cbuf[l'][b]
    if (wm == (c >> 1)) {
      #pragma unroll
      for (int d = 0; d < 4; ++d) {
        int mf = ((c & 1) << 2) + d;
        #pragma unroll
        for (int nf = 0; nf < 2; ++nf) {
          int bc = (wn << 5) + (nf << 4) + bl;
          #pragma unroll
          for (int r = 0; r < 4; ++r) {
            int lr = (d << 4) + (kh << 2) + r;
            cbuf[lr * CSTR + bc] = acc[mf][nf][r];
          }
        }
      }
    }
    __syncthreads();
    if (t < 128) {
      for (int lc = 0; lc < 64; lc += 4) {
        float v[4];
        #pragma unroll
        for (int u = 0; u < 4; ++u) v[u] = cbuf[(lc + u) * CSTR + t];
        #pragma unroll
        for (int u = 0; u < 4; ++u) {
          int l = (c << 6) + lc + u;
          carry = (l == 0) ? v[u] : combine_step(carry, v[u], cprm + ((l - 1) << 3));
        }
      }
    }
  }
  if (t < 128) out[b0 + t] = carry;
}

// ---------------- launch ----------------
extern "C" void kernel_launch(void* const* d_in, const int* in_sizes, int n_in,
                              void* d_out, int out_size, void* d_ws, size_t ws_size,
                              hipStream_t stream) {
  const float* x       = (const float*)d_in[0];   // (65536, 256)
  const float* logits  = (const float*)d_in[1];   // (256, 256)
  const float* weights = (const float*)d_in[2];   // (255, 2)
  const float* biases  = (const float*)d_in[3];   // (255,)
  float* out = (float*)d_out;                     // (65536, 1)

  char* ws = (char*)d_ws;
  u16*   PTf = (u16*)ws;                          // 131072 B (fp16 P^T)
  float* prm = (float*)(ws + 131072);             // 8160 B

  int Btot = in_sizes[0] / 256;                   // 65536

  param_kernel<<<1, 256, 0, stream>>>(weights, biases, prm, 255);
  sinkhorn_kernel<<<1, 1024, 0, stream>>>(logits, PTf);
  gemm_chain_kernel<<<Btot / 128, 512, 0, stream>>>(x, PTf, prm, out);
}